// Round 5
// baseline (88548.212 us; speedup 1.0000x reference)
//
#include <hip/hip_runtime.h>
#include <hip/hip_cooperative_groups.h>

namespace cg = cooperative_groups;

typedef __bf16 bf16x8 __attribute__((ext_vector_type(8)));
typedef float floatx4 __attribute__((ext_vector_type(4)));
typedef unsigned short u16;

// Sizes: SEQ=256, B=32, NHID=1024, NTOK=32000, NHEADS=4, HD=256
// xi row layout (4096): [emb 0:1024 | q 1024:2048 | attn 2048:3072 | hidden 3072:4096]
// I/O: inputs fp32 (obs int32), output fp32.
// Numerics: recurrence GEMMs via bf16x3 split MFMA (~fp32 accurate);
// attention/LN/softmax fully fp32; decoder plain bf16 MFMA (non-recurrent).
// Grid: 256 blocks x 512 threads (8 waves), 1 block/CU. 6 grid syncs/step.
// Every GEMM phase is spread wave-major across ALL blocks (each block = 1 CU).

__device__ inline float bf2f(u16 h) { return __uint_as_float(((unsigned)h) << 16); }
__device__ inline u16 f2bf(float f) {
  unsigned u = __float_as_uint(f);
  u += 0x7fffu + ((u >> 16) & 1u);   // RNE
  return (u16)(u >> 16);
}
__device__ inline void wr_split(u16* hi, u16* lo, size_t idx, float v) {
  u16 h = f2bf(v);
  hi[idx] = h;
  lo[idx] = f2bf(v - bf2f(h));
}
__device__ inline void wr_split4(u16* hi, u16* lo, size_t idx, float4 v) {
  ushort4 h, l;
  h.x = f2bf(v.x); l.x = f2bf(v.x - bf2f(h.x));
  h.y = f2bf(v.y); l.y = f2bf(v.y - bf2f(h.y));
  h.z = f2bf(v.z); l.z = f2bf(v.z - bf2f(h.z));
  h.w = f2bf(v.w); l.w = f2bf(v.w - bf2f(h.w));
  *(ushort4*)(hi + idx) = h;
  *(ushort4*)(lo + idx) = l;
}

__device__ inline float wred_add(float v) {
#pragma unroll
  for (int m = 32; m; m >>= 1) v += __shfl_xor(v, m, 64);
  return v;
}
__device__ inline float wred_max(float v) {
#pragma unroll
  for (int m = 32; m; m >>= 1) v = fmaxf(v, __shfl_xor(v, m, 64));
  return v;
}
// 512-thread (8-wave) block reductions
__device__ inline float bred_add(float v, float* red, int tid) {
  v = wred_add(v);
  if ((tid & 63) == 0) red[tid >> 6] = v;
  __syncthreads();
  v = (red[0] + red[1]) + (red[2] + red[3]) + ((red[4] + red[5]) + (red[6] + red[7]));
  __syncthreads();
  return v;
}
__device__ inline float bred_max(float v, float* red, int tid) {
  v = wred_max(v);
  if ((tid & 63) == 0) red[tid >> 6] = v;
  __syncthreads();
  v = fmaxf(fmaxf(fmaxf(red[0], red[1]), fmaxf(red[2], red[3])),
            fmaxf(fmaxf(red[4], red[5]), fmaxf(red[6], red[7])));
  __syncthreads();
  return v;
}

struct Prm {
  const int* obs;
  const float* emb;
  const u16 *qwh, *qwl;
  const float *qb, *qg, *qbt;
  const u16 *iwh, *iwl;
  const float *ib, *ig, *ibt;
  const u16 *fwh, *fwl;
  const float *fb, *fg, *fbt;
  const float *hid0, *key0, *val0;
  u16 *xih, *xil, *interh, *interl, *states;
  float *keys, *vals;
  float *qpart, *ip1, *ip2, *finpart;
};

// fp32 -> bf16 (n4 = float4 count)
__global__ void cvt_bf16(const float* __restrict__ in, u16* __restrict__ out, int n4) {
  int idx = blockIdx.x * blockDim.x + threadIdx.x;
  int stride = gridDim.x * blockDim.x;
  for (int i = idx; i < n4; i += stride) {
    float4 v = ((const float4*)in)[i];
    ushort4 s;
    s.x = f2bf(v.x); s.y = f2bf(v.y); s.z = f2bf(v.z); s.w = f2bf(v.w);
    ((ushort4*)out)[i] = s;
  }
}
// fp32 -> bf16 hi/lo split
__global__ void cvt_split(const float* __restrict__ in, u16* __restrict__ hi,
                          u16* __restrict__ lo, int n4) {
  int idx = blockIdx.x * blockDim.x + threadIdx.x;
  int stride = gridDim.x * blockDim.x;
  for (int i = idx; i < n4; i += stride) {
    float4 v = ((const float4*)in)[i];
    wr_split4(hi, lo, (size_t)i * 4, v);
  }
}

// One wave: [32 x 16] fp32 tile of OUT = A(32 x K) * W(N x K)^T over nk32*32 of K,
// with A,W as bf16 hi/lo splits: hi*hi + hi*lo + lo*hi (~fp32-accurate).
// mfma_f32_16x16x32_bf16: a-frag lane l holds A[l&15][8*(l>>4)+j];
// c: row = 4*(l>>4)+r, col = l&15.
__device__ inline void mm_tile3(const u16* __restrict__ Ah, const u16* __restrict__ Al,
                                int lda, int acol0,
                                const u16* __restrict__ Wh, const u16* __restrict__ Wl,
                                int ldw, int wrow0, int wcol0,
                                int nk32, int lane, floatx4& c0, floatx4& c1) {
  const int fr = lane & 15, kg = lane >> 4;
  const size_t aoff = (size_t)fr * lda + acol0 + kg * 8;
  const size_t woff = (size_t)(wrow0 + fr) * ldw + wcol0 + kg * 8;
  const u16* pah = Ah + aoff;
  const u16* pal = Al + aoff;
  const u16* pwh = Wh + woff;
  const u16* pwl = Wl + woff;
  const size_t a16 = (size_t)16 * lda;
  c0 = floatx4{0.f, 0.f, 0.f, 0.f};
  c1 = floatx4{0.f, 0.f, 0.f, 0.f};
#pragma unroll 4
  for (int t = 0; t < nk32; ++t) {
    bf16x8 ah0 = *(const bf16x8*)pah;
    bf16x8 ah1 = *(const bf16x8*)(pah + a16);
    bf16x8 al0 = *(const bf16x8*)pal;
    bf16x8 al1 = *(const bf16x8*)(pal + a16);
    bf16x8 wh  = *(const bf16x8*)pwh;
    bf16x8 wl  = *(const bf16x8*)pwl;
    c0 = __builtin_amdgcn_mfma_f32_16x16x32_bf16(ah0, wh, c0, 0, 0, 0);
    c1 = __builtin_amdgcn_mfma_f32_16x16x32_bf16(ah1, wh, c1, 0, 0, 0);
    c0 = __builtin_amdgcn_mfma_f32_16x16x32_bf16(ah0, wl, c0, 0, 0, 0);
    c1 = __builtin_amdgcn_mfma_f32_16x16x32_bf16(ah1, wl, c1, 0, 0, 0);
    c0 = __builtin_amdgcn_mfma_f32_16x16x32_bf16(al0, wh, c0, 0, 0, 0);
    c1 = __builtin_amdgcn_mfma_f32_16x16x32_bf16(al1, wh, c1, 0, 0, 0);
    pah += 32; pal += 32; pwh += 32; pwl += 32;
  }
}

__device__ inline void store_part(float* outp, int ld, int nt, int lane,
                                  const floatx4& c0, const floatx4& c1) {
  int col = nt * 16 + (lane & 15), kg = lane >> 4;
#pragma unroll
  for (int r = 0; r < 4; ++r) {
    outp[(kg * 4 + r) * ld + col] = c0[r];
    outp[(kg * 4 + r + 16) * ld + col] = c1[r];
  }
}

// ---------------- cooperative recurrence kernel ----------------
__global__ void __launch_bounds__(512, 2) rnn_kernel(Prm p) {
  cg::grid_group grid = cg::this_grid();
  __shared__ float sm[2080];
  float* qrow = sm;            // 1024
  float* qn   = sm + 1024;     // 256
  float* sc   = sm + 1280;     // 257
  float* pv   = sm + 1544;     // 512
  float* red  = sm + 2056;     // 8
  const int blk = blockIdx.x, tid = threadIdx.x;
  const int lane = tid & 63, wv = tid >> 6;

  // ---- init: emb step 0 + hidden0 -> xi; KV slot 0 ----
  if (blk < 32) {
    int b = blk;
    if (tid < 256) {
      int tok = p.obs[b];
      float4 e4 = ((const float4*)(p.emb + (size_t)tok * 1024))[tid];
      wr_split4(p.xih, p.xil, (size_t)b * 4096 + 4 * tid, e4);
      float4 h4 = ((const float4*)(p.hid0 + (size_t)b * 1024))[tid];
      wr_split4(p.xih, p.xil, (size_t)b * 4096 + 3072 + 4 * tid, h4);
    }
  } else if (blk < 64) {
    int b = blk - 32;
    for (int e = tid; e < 1024; e += 512) {
      p.keys[(size_t)b * 1024 + e] = p.key0[(size_t)b * 1024 + e];
      p.vals[(size_t)b * 1024 + e] = p.val0[(size_t)b * 1024 + e];
    }
  }
  grid.sync();

  for (int i = 0; i < 256; ++i) {
    // ---- P1: q-GEMM (K=2048 over [emb|hidden], 64 ntiles x 8 ksplit) ----
    if (wv < 2) {
      int w = wv * 256 + blk;          // 0..511
      int nt = w & 63, kc = w >> 6;    // kc 0..7, K-chunk 256
      int acol = (kc < 4) ? kc * 256 : 3072 + (kc - 4) * 256;
      int wcol = (kc < 4) ? kc * 256 : 1024 + (kc - 4) * 256;
      floatx4 c0, c1;
      mm_tile3(p.xih, p.xil, 4096, acol, p.qwh, p.qwl, 2048, nt * 16, wcol,
               8, lane, c0, c1);
      store_part(p.qpart + (size_t)kc * 32 * 1024, 1024, nt, lane, c0, c1);
    }
    grid.sync();

    // ---- P2: attention (+ LN-q) on blocks 0..127 || int-GEMM emb+hid half on 128..255 ----
    if (blk < 128) {
      int b = blk >> 2, h = blk & 3;
      float s1 = 0.f, s2 = 0.f;
      for (int e = tid; e < 1024; e += 512) {
        size_t o = (size_t)b * 1024 + e;
        float v = ((p.qpart[o] + p.qpart[32768 + o]) +
                   (p.qpart[65536 + o] + p.qpart[98304 + o])) +
                  ((p.qpart[131072 + o] + p.qpart[163840 + o]) +
                   (p.qpart[196608 + o] + p.qpart[229376 + o])) + p.qb[e];
        qrow[e] = v; s1 += v; s2 += v * v;
      }
      __syncthreads();
      s1 = bred_add(s1, red, tid);
      s2 = bred_add(s2, red, tid);
      float mu = s1 * (1.f / 1024.f);
      float rs = rsqrtf(s2 * (1.f / 1024.f) - mu * mu + 1e-5f);
      if (tid < 256) {
        int e = h * 256 + tid;
        float y = fmaxf((qrow[e] - mu) * rs * p.qg[e] + p.qbt[e], 0.f);
        qn[tid] = y;
        wr_split(p.xih, p.xil, (size_t)b * 4096 + 1024 + e, y);
      }
      __syncthreads();
      // scores over slots 0..i; scale = 1/(16*0.1) = 0.625
      for (int s = wv; s <= i; s += 8) {
        const float* kp = p.keys + ((size_t)s * 32 + b) * 1024 + h * 256 + lane * 4;
        float4 k4 = *(const float4*)kp;
        float pd = qn[lane * 4] * k4.x + qn[lane * 4 + 1] * k4.y +
                   qn[lane * 4 + 2] * k4.z + qn[lane * 4 + 3] * k4.w;
        pd = wred_add(pd);
        if (lane == 0) sc[s] = pd * 0.625f;
      }
      __syncthreads();
      float mx = (tid <= i) ? sc[tid] : -1e30f;
      mx = bred_max(mx, red, tid);
      float sum = 0.f;
      if (tid <= i) { float e = expf(sc[tid] - mx); sc[tid] = e; sum = e; }
      sum = bred_add(sum, red, tid);
      float inv = 1.f / sum;
      {
        float acc = 0.f;
        int d = tid & 255, half = tid >> 8;
        const float* vp = p.vals + (size_t)b * 1024 + h * 256 + d;
#pragma unroll 4
        for (int s = half; s <= i; s += 2) acc += sc[s] * vp[(size_t)s * 32768];
        pv[tid] = acc;
      }
      __syncthreads();
      if (tid < 256) {
        float val = (pv[tid] + pv[tid + 256]) * inv;
        wr_split(p.xih, p.xil, (size_t)b * 4096 + 2048 + h * 256 + tid, val);
      }
    } else {
      int w = (blk - 128) * 8 + wv;    // 0..1023
      int nt = w & 255, kc = w >> 8;   // kc 0..3, K-chunk 512
      int col0 = (kc < 2) ? kc * 512 : 3072 + (kc - 2) * 512;
      floatx4 c0, c1;
      mm_tile3(p.xih, p.xil, 4096, col0, p.iwh, p.iwl, 4096, nt * 16, col0,
               16, lane, c0, c1);
      store_part(p.ip1 + (size_t)kc * 32 * 4096, 4096, nt, lane, c0, c1);
    }
    grid.sync();

    // ---- P3: int-GEMM q+attn half (256 ntiles x 8 ksplit, all blocks) ----
    {
      int w = blk * 8 + wv;            // 0..2047
      int nt = w & 255, kc = w >> 8;   // kc 0..7, K-chunk 256
      int col0 = 1024 + kc * 256;
      floatx4 c0, c1;
      mm_tile3(p.xih, p.xil, 4096, col0, p.iwh, p.iwl, 4096, nt * 16, col0,
               8, lane, c0, c1);
      store_part(p.ip2 + (size_t)kc * 32 * 4096, 4096, nt, lane, c0, c1);
    }
    grid.sync();

    // ---- P4: LN-int (blocks 0..31) || emb gather i+1 (blocks 32..63) ----
    if (blk < 32) {
      int b = blk;
      float xs[8], s1 = 0.f, s2 = 0.f;
#pragma unroll
      for (int j = 0; j < 8; ++j) {
        int e = tid + j * 512;
        size_t o = (size_t)b * 4096 + e;
        float x = ((p.ip1[o] + p.ip1[131072 + o]) +
                   (p.ip1[262144 + o] + p.ip1[393216 + o])) +
                  ((p.ip2[o] + p.ip2[131072 + o]) +
                   (p.ip2[262144 + o] + p.ip2[393216 + o])) +
                  ((p.ip2[524288 + o] + p.ip2[655360 + o]) +
                   (p.ip2[786432 + o] + p.ip2[917504 + o])) + p.ib[e];
        xs[j] = x; s1 += x; s2 += x * x;
      }
      s1 = bred_add(s1, red, tid);
      s2 = bred_add(s2, red, tid);
      float mu = s1 * (1.f / 4096.f);
      float rs = rsqrtf(s2 * (1.f / 4096.f) - mu * mu + 1e-5f);
#pragma unroll
      for (int j = 0; j < 8; ++j) {
        int e = tid + j * 512;
        float y = fmaxf((xs[j] - mu) * rs * p.ig[e] + p.ibt[e], 0.f);
        wr_split(p.interh, p.interl, (size_t)b * 4096 + e, y);
      }
    } else if (blk < 64) {
      if (i + 1 < 256 && tid < 256) {
        int b = blk - 32;
        int tok = p.obs[(i + 1) * 32 + b];
        float4 e4 = ((const float4*)(p.emb + (size_t)tok * 1024))[tid];
        wr_split4(p.xih, p.xil, (size_t)b * 4096 + 4 * tid, e4);
      }
    }
    grid.sync();

    // ---- P5: fin-GEMM (192 ntiles x 8 ksplit over waves 0..5 of all blocks) ----
    if (wv < 6) {
      int w = wv * 256 + blk;          // 0..1535
      int nt = w % 192, kc = w / 192;  // kc 0..7, K-chunk 512
      floatx4 c0, c1;
      mm_tile3(p.interh, p.interl, 4096, kc * 512, p.fwh, p.fwl, 4096, nt * 16,
               kc * 512, 16, lane, c0, c1);
      store_part(p.finpart + (size_t)kc * 32 * 3072, 3072, nt, lane, c0, c1);
    }
    grid.sync();

    // ---- P6: merge fin + LN; write keys/vals slot i+1, hidden -> xi & states ----
    if (blk < 32) {
      int b = blk;
      float xs[6], s1 = 0.f, s2 = 0.f;
#pragma unroll
      for (int j = 0; j < 6; ++j) {
        int e = tid + j * 512;
        size_t o = (size_t)b * 3072 + e;
        float x = ((p.finpart[o] + p.finpart[98304 + o]) +
                   (p.finpart[196608 + o] + p.finpart[294912 + o])) +
                  ((p.finpart[393216 + o] + p.finpart[491520 + o]) +
                   (p.finpart[589824 + o] + p.finpart[688128 + o])) + p.fb[e];
        xs[j] = x; s1 += x; s2 += x * x;
      }
      s1 = bred_add(s1, red, tid);
      s2 = bred_add(s2, red, tid);
      float mu = s1 * (1.f / 3072.f);
      float rs = rsqrtf(s2 * (1.f / 3072.f) - mu * mu + 1e-5f);
#pragma unroll
      for (int j = 0; j < 6; ++j) {
        int e = tid + j * 512;
        float y = fmaxf((xs[j] - mu) * rs * p.fg[e] + p.fbt[e], 0.f);
        if (j < 2) {
          p.keys[((size_t)(i + 1) * 32 + b) * 1024 + e] = y;
        } else if (j < 4) {
          p.vals[((size_t)(i + 1) * 32 + b) * 1024 + (e - 1024)] = y;
        } else {
          int d = e - 2048;
          wr_split(p.xih, p.xil, (size_t)b * 4096 + 3072 + d, y);
          p.states[((size_t)i * 32 + b) * 1024 + d] = f2bf(y);
        }
      }
    }
    grid.sync();
  }
}

// ---------------- decoder GEMM: logits = states @ dec_w^T + dec_b ----------------
// M=8192, N=32000, K=1024 bf16. 128x128 tiles, BK=32, dbuf LDS (stride 40), XCD swizzle.
__global__ void __launch_bounds__(256) dec_gemm(const u16* __restrict__ Sm,
                                                const u16* __restrict__ W,
                                                const float* __restrict__ Wb,
                                                float* __restrict__ out) {
  __shared__ u16 As[2][128 * 40];
  __shared__ u16 Bs[2][128 * 40];
  int bid = blockIdx.x;                      // 16000 % 8 == 0
  int swz = (bid & 7) * 2000 + (bid >> 3);
  int mt = swz / 250, nt = swz - mt * 250;
  const int tid = threadIdx.x;
  const int lane = tid & 63, wvi = tid >> 6;
  const int wm = wvi >> 1, wn = wvi & 1;
  const int fr = lane & 15, fg = lane >> 4;

  const int r0 = tid >> 2, k0 = (tid & 3) * 8;
  const u16* pa0 = Sm + (size_t)(mt * 128 + r0) * 1024 + k0;
  const u16* pa1 = pa0 + (size_t)64 * 1024;
  const u16* pb0 = W + (size_t)(nt * 128 + r0) * 1024 + k0;
  const u16* pb1 = pb0 + (size_t)64 * 1024;
  const int da0 = r0 * 40 + k0, da1 = (r0 + 64) * 40 + k0;

  floatx4 acc[4][4];
#pragma unroll
  for (int i = 0; i < 4; ++i)
#pragma unroll
    for (int j = 0; j < 4; ++j) acc[i][j] = floatx4{0.f, 0.f, 0.f, 0.f};

  uint4 ra0 = *(const uint4*)pa0, ra1 = *(const uint4*)pa1;
  uint4 rb0 = *(const uint4*)pb0, rb1 = *(const uint4*)pb1;
  *(uint4*)&As[0][da0] = ra0; *(uint4*)&As[0][da1] = ra1;
  *(uint4*)&Bs[0][da0] = rb0; *(uint4*)&Bs[0][da1] = rb1;
  __syncthreads();

  for (int kt = 0; kt < 32; ++kt) {
    const int cur = kt & 1;
    if (kt < 31) {
      const int off = (kt + 1) * 32;
      ra0 = *(const uint4*)(pa0 + off); ra1 = *(const uint4*)(pa1 + off);
      rb0 = *(const uint4*)(pb0 + off); rb1 = *(const uint4*)(pb1 + off);
    }
    bf16x8 af[4], bfv[4];
#pragma unroll
    for (int i = 0; i < 4; ++i) {
      af[i]  = *(const bf16x8*)&As[cur][(wm * 64 + i * 16 + fr) * 40 + fg * 8];
      bfv[i] = *(const bf16x8*)&Bs[cur][(wn * 64 + i * 16 + fr) * 40 + fg * 8];
    }
#pragma unroll
    for (int i = 0; i < 4; ++i)
#pragma unroll
      for (int j = 0; j < 4; ++j)
        acc[i][j] = __builtin_amdgcn_mfma_f32_16x16x32_bf16(af[i], bfv[j], acc[i][j], 0, 0, 0);
    if (kt < 31) {
      *(uint4*)&As[cur ^ 1][da0] = ra0; *(uint4*)&As[cur ^ 1][da1] = ra1;
      *(uint4*)&Bs[cur ^ 1][da0] = rb0; *(uint4*)&Bs[cur ^ 1][da1] = rb1;
    }
    __syncthreads();
  }

#pragma unroll
  for (int i = 0; i < 4; ++i)
#pragma unroll
    for (int j = 0; j < 4; ++j) {
      int col = nt * 128 + wn * 64 + j * 16 + fr;
      float bias = Wb[col];
#pragma unroll
      for (int r = 0; r < 4; ++r) {
        int row = mt * 128 + wm * 64 + i * 16 + fg * 4 + r;
        out[(size_t)row * 32000 + col] = acc[i][j][r] + bias;
      }
    }
}

extern "C" void kernel_launch(void* const* d_in, const int* in_sizes, int n_in,
                              void* d_out, int out_size, void* d_ws, size_t ws_size,
                              hipStream_t stream) {
  (void)in_sizes; (void)n_in; (void)out_size; (void)ws_size;
  char* ws = (char*)d_ws;
  size_t off = 0;
  auto carve = [&](size_t bytes) {
    void* pp = ws + off;
    off += (bytes + 255) & ~(size_t)255;
    return pp;
  };
  u16* qwh       = (u16*)carve((size_t)1024 * 2048 * 2);
  u16* qwl       = (u16*)carve((size_t)1024 * 2048 * 2);
  u16* iwh       = (u16*)carve((size_t)4096 * 4096 * 2);
  u16* iwl       = (u16*)carve((size_t)4096 * 4096 * 2);
  u16* fwh       = (u16*)carve((size_t)3072 * 4096 * 2);
  u16* fwl       = (u16*)carve((size_t)3072 * 4096 * 2);
  u16* xih       = (u16*)carve((size_t)32 * 4096 * 2);
  u16* xil       = (u16*)carve((size_t)32 * 4096 * 2);
  u16* interh    = (u16*)carve((size_t)32 * 4096 * 2);
  u16* interl    = (u16*)carve((size_t)32 * 4096 * 2);
  float* qpart   = (float*)carve((size_t)8 * 32 * 1024 * 4);
  float* ip1     = (float*)carve((size_t)4 * 32 * 4096 * 4);
  float* ip2     = (float*)carve((size_t)8 * 32 * 4096 * 4);
  float* finpart = (float*)carve((size_t)8 * 32 * 3072 * 4);
  float* keysF   = (float*)carve((size_t)257 * 32 * 1024 * 4);
  float* valsF   = (float*)carve((size_t)257 * 32 * 1024 * 4);
  u16* states    = (u16*)carve((size_t)256 * 32 * 1024 * 2);
  // total ~220 MB. dec_w bf16 (65.5 MB) converted AFTER the RNN into the
  // then-dead q/int weight region at offset 0.
  u16* dw_bf = (u16*)ws;

  // weight hi/lo splits
  cvt_split<<<dim3(512), dim3(256), 0, stream>>>((const float*)d_in[2], qwh, qwl, 1024 * 2048 / 4);
  cvt_split<<<dim3(2048), dim3(256), 0, stream>>>((const float*)d_in[6], iwh, iwl, 4096 * 4096 / 4);
  cvt_split<<<dim3(2048), dim3(256), 0, stream>>>((const float*)d_in[10], fwh, fwl, 3072 * 4096 / 4);

  Prm prm;
  prm.obs = (const int*)d_in[0];
  prm.emb = (const float*)d_in[1];
  prm.qwh = qwh; prm.qwl = qwl;
  prm.qb  = (const float*)d_in[3];
  prm.qg  = (const float*)d_in[4];
  prm.qbt = (const float*)d_in[5];
  prm.iwh = iwh; prm.iwl = iwl;
  prm.ib  = (const float*)d_in[7];
  prm.ig  = (const float*)d_in[8];
  prm.ibt = (const float*)d_in[9];
  prm.fwh = fwh; prm.fwl = fwl;
  prm.fb  = (const float*)d_in[11];
  prm.fg  = (const float*)d_in[12];
  prm.fbt = (const float*)d_in[13];
  prm.hid0 = (const float*)d_in[16];
  prm.key0 = (const float*)d_in[17];
  prm.val0 = (const float*)d_in[18];
  prm.xih = xih; prm.xil = xil; prm.interh = interh; prm.interl = interl;
  prm.states = states; prm.keys = keysF; prm.vals = valsF;
  prm.qpart = qpart; prm.ip1 = ip1; prm.ip2 = ip2; prm.finpart = finpart;

  void* args[] = { &prm };
  hipLaunchCooperativeKernel(rnn_kernel, dim3(256), dim3(512), args, 0, stream);

  // dec_w fp32 -> bf16 into reused region (q/int weights dead after RNN)
  cvt_bf16<<<dim3(4096), dim3(256), 0, stream>>>((const float*)d_in[14], dw_bf, 32000 * 1024 / 4);

  dec_gemm<<<dim3(16000), dim3(256), 0, stream>>>(
      states, dw_bf, (const float*)d_in[15], (float*)d_out);
}

// Round 6
// 23863.715 us; speedup vs baseline: 3.7106x; 3.7106x over previous
//
#include <hip/hip_runtime.h>

typedef __bf16 bf16x8 __attribute__((ext_vector_type(8)));
typedef float floatx4 __attribute__((ext_vector_type(4)));
typedef unsigned short u16;

// Sizes: SEQ=256, B=32, NHID=1024, NTOK=32000, NHEADS=4, HD=256
// xi row layout (4096): [emb 0:1024 | q 1024:2048 | attn 2048:3072 | hidden 3072:4096]
// I/O: inputs fp32 (obs int32), output fp32.
// Numerics: recurrence GEMMs via bf16x3 split MFMA (~fp32 accurate);
// attention/LN/softmax fully fp32; decoder plain bf16 MFMA (non-recurrent).
// Structure: per-phase kernels (6/step), stream-ordered -> kernel-boundary
// coherence replaces the ~50us cg::grid.sync() measured in rounds 4/5.

__device__ inline float bf2f(u16 h) { return __uint_as_float(((unsigned)h) << 16); }
__device__ inline u16 f2bf(float f) {
  unsigned u = __float_as_uint(f);
  u += 0x7fffu + ((u >> 16) & 1u);   // RNE
  return (u16)(u >> 16);
}
__device__ inline void wr_split(u16* hi, u16* lo, size_t idx, float v) {
  u16 h = f2bf(v);
  hi[idx] = h;
  lo[idx] = f2bf(v - bf2f(h));
}
__device__ inline void wr_split4(u16* hi, u16* lo, size_t idx, float4 v) {
  ushort4 h, l;
  h.x = f2bf(v.x); l.x = f2bf(v.x - bf2f(h.x));
  h.y = f2bf(v.y); l.y = f2bf(v.y - bf2f(h.y));
  h.z = f2bf(v.z); l.z = f2bf(v.z - bf2f(h.z));
  h.w = f2bf(v.w); l.w = f2bf(v.w - bf2f(h.w));
  *(ushort4*)(hi + idx) = h;
  *(ushort4*)(lo + idx) = l;
}

__device__ inline float wred_add(float v) {
#pragma unroll
  for (int m = 32; m; m >>= 1) v += __shfl_xor(v, m, 64);
  return v;
}
__device__ inline float wred_max(float v) {
#pragma unroll
  for (int m = 32; m; m >>= 1) v = fmaxf(v, __shfl_xor(v, m, 64));
  return v;
}
// 512-thread (8-wave) block reductions
__device__ inline float bred_add(float v, float* red, int tid) {
  v = wred_add(v);
  if ((tid & 63) == 0) red[tid >> 6] = v;
  __syncthreads();
  v = (red[0] + red[1]) + (red[2] + red[3]) + ((red[4] + red[5]) + (red[6] + red[7]));
  __syncthreads();
  return v;
}
__device__ inline float bred_max(float v, float* red, int tid) {
  v = wred_max(v);
  if ((tid & 63) == 0) red[tid >> 6] = v;
  __syncthreads();
  v = fmaxf(fmaxf(fmaxf(red[0], red[1]), fmaxf(red[2], red[3])),
            fmaxf(fmaxf(red[4], red[5]), fmaxf(red[6], red[7])));
  __syncthreads();
  return v;
}

struct Prm {
  const int* obs;
  const float* emb;
  const u16 *qwh, *qwl;
  const float *qb, *qg, *qbt;
  const u16 *iwh, *iwl;
  const float *ib, *ig, *ibt;
  const u16 *fwh, *fwl;
  const float *fb, *fg, *fbt;
  const float *hid0, *key0, *val0;
  u16 *xih, *xil, *interh, *interl, *states;
  float *keys, *vals;
  float *qpart, *ip1, *ip2, *finpart;
};

// fp32 -> bf16 (n4 = float4 count)
__global__ void cvt_bf16(const float* __restrict__ in, u16* __restrict__ out, int n4) {
  int idx = blockIdx.x * blockDim.x + threadIdx.x;
  int stride = gridDim.x * blockDim.x;
  for (int i = idx; i < n4; i += stride) {
    float4 v = ((const float4*)in)[i];
    ushort4 s;
    s.x = f2bf(v.x); s.y = f2bf(v.y); s.z = f2bf(v.z); s.w = f2bf(v.w);
    ((ushort4*)out)[i] = s;
  }
}
// fp32 -> bf16 hi/lo split
__global__ void cvt_split(const float* __restrict__ in, u16* __restrict__ hi,
                          u16* __restrict__ lo, int n4) {
  int idx = blockIdx.x * blockDim.x + threadIdx.x;
  int stride = gridDim.x * blockDim.x;
  for (int i = idx; i < n4; i += stride) {
    float4 v = ((const float4*)in)[i];
    wr_split4(hi, lo, (size_t)i * 4, v);
  }
}

// One wave: [32 x 16] fp32 tile of OUT = A(32 x K) * W(N x K)^T over nk32*32 of K,
// A,W as bf16 hi/lo splits: hi*hi + hi*lo + lo*hi (~fp32-accurate).
// mfma_f32_16x16x32_bf16: a-frag lane l holds A[l&15][8*(l>>4)+j];
// c: row = 4*(l>>4)+r, col = l&15.
__device__ inline void mm_tile3(const u16* __restrict__ Ah, const u16* __restrict__ Al,
                                int lda, int acol0,
                                const u16* __restrict__ Wh, const u16* __restrict__ Wl,
                                int ldw, int wrow0, int wcol0,
                                int nk32, int lane, floatx4& c0, floatx4& c1) {
  const int fr = lane & 15, kg = lane >> 4;
  const size_t aoff = (size_t)fr * lda + acol0 + kg * 8;
  const size_t woff = (size_t)(wrow0 + fr) * ldw + wcol0 + kg * 8;
  const u16* pah = Ah + aoff;
  const u16* pal = Al + aoff;
  const u16* pwh = Wh + woff;
  const u16* pwl = Wl + woff;
  const size_t a16 = (size_t)16 * lda;
  c0 = floatx4{0.f, 0.f, 0.f, 0.f};
  c1 = floatx4{0.f, 0.f, 0.f, 0.f};
#pragma unroll 4
  for (int t = 0; t < nk32; ++t) {
    bf16x8 ah0 = *(const bf16x8*)pah;
    bf16x8 ah1 = *(const bf16x8*)(pah + a16);
    bf16x8 al0 = *(const bf16x8*)pal;
    bf16x8 al1 = *(const bf16x8*)(pal + a16);
    bf16x8 wh  = *(const bf16x8*)pwh;
    bf16x8 wl  = *(const bf16x8*)pwl;
    c0 = __builtin_amdgcn_mfma_f32_16x16x32_bf16(ah0, wh, c0, 0, 0, 0);
    c1 = __builtin_amdgcn_mfma_f32_16x16x32_bf16(ah1, wh, c1, 0, 0, 0);
    c0 = __builtin_amdgcn_mfma_f32_16x16x32_bf16(ah0, wl, c0, 0, 0, 0);
    c1 = __builtin_amdgcn_mfma_f32_16x16x32_bf16(ah1, wl, c1, 0, 0, 0);
    c0 = __builtin_amdgcn_mfma_f32_16x16x32_bf16(al0, wh, c0, 0, 0, 0);
    c1 = __builtin_amdgcn_mfma_f32_16x16x32_bf16(al1, wh, c1, 0, 0, 0);
    pah += 32; pal += 32; pwh += 32; pwl += 32;
  }
}

__device__ inline void store_part(float* outp, int ld, int nt, int lane,
                                  const floatx4& c0, const floatx4& c1) {
  int col = nt * 16 + (lane & 15), kg = lane >> 4;
#pragma unroll
  for (int r = 0; r < 4; ++r) {
    outp[(kg * 4 + r) * ld + col] = c0[r];
    outp[(kg * 4 + r + 16) * ld + col] = c1[r];
  }
}

// ---- init: emb step 0 + hidden0 -> xi; KV slot 0 ----  grid 64
__global__ void __launch_bounds__(512) k_init(Prm p) {
  const int blk = blockIdx.x, tid = threadIdx.x;
  if (blk < 32) {
    int b = blk;
    if (tid < 256) {
      int tok = p.obs[b];
      float4 e4 = ((const float4*)(p.emb + (size_t)tok * 1024))[tid];
      wr_split4(p.xih, p.xil, (size_t)b * 4096 + 4 * tid, e4);
      float4 h4 = ((const float4*)(p.hid0 + (size_t)b * 1024))[tid];
      wr_split4(p.xih, p.xil, (size_t)b * 4096 + 3072 + 4 * tid, h4);
    }
  } else {
    int b = blk - 32;
    for (int e = tid; e < 1024; e += 512) {
      p.keys[(size_t)b * 1024 + e] = p.key0[(size_t)b * 1024 + e];
      p.vals[(size_t)b * 1024 + e] = p.val0[(size_t)b * 1024 + e];
    }
  }
}

// ---- P1: q-GEMM (K=2048 over [emb|hidden], 64 ntiles x 8 ksplit) ---- grid 64
__global__ void __launch_bounds__(512) k_q(Prm p, int i) {
  const int tid = threadIdx.x, lane = tid & 63, wv = tid >> 6;
  int w = blockIdx.x * 8 + wv;     // 0..511
  int nt = w & 63, kc = w >> 6;    // kc 0..7, K-chunk 256
  int acol = (kc < 4) ? kc * 256 : 3072 + (kc - 4) * 256;
  int wcol = (kc < 4) ? kc * 256 : 1024 + (kc - 4) * 256;
  floatx4 c0, c1;
  mm_tile3(p.xih, p.xil, 4096, acol, p.qwh, p.qwl, 2048, nt * 16, wcol,
           8, lane, c0, c1);
  store_part(p.qpart + (size_t)kc * 32 * 1024, 1024, nt, lane, c0, c1);
}

// ---- P2: attention (+ LN-q) blocks 0..127 || int-GEMM emb+hid half 128..255 ----
__global__ void __launch_bounds__(512) k_attn_int1(Prm p, int i) {
  __shared__ float sm[2080];
  float* qrow = sm;            // 1024
  float* qn   = sm + 1024;     // 256
  float* sc   = sm + 1280;     // 257
  float* pv   = sm + 1544;     // 512
  float* red  = sm + 2056;     // 8
  const int blk = blockIdx.x, tid = threadIdx.x;
  const int lane = tid & 63, wv = tid >> 6;

  if (blk < 128) {
    int b = blk >> 2, h = blk & 3;
    float s1 = 0.f, s2 = 0.f;
    for (int e = tid; e < 1024; e += 512) {
      size_t o = (size_t)b * 1024 + e;
      float v = ((p.qpart[o] + p.qpart[32768 + o]) +
                 (p.qpart[65536 + o] + p.qpart[98304 + o])) +
                ((p.qpart[131072 + o] + p.qpart[163840 + o]) +
                 (p.qpart[196608 + o] + p.qpart[229376 + o])) + p.qb[e];
      qrow[e] = v; s1 += v; s2 += v * v;
    }
    __syncthreads();
    s1 = bred_add(s1, red, tid);
    s2 = bred_add(s2, red, tid);
    float mu = s1 * (1.f / 1024.f);
    float rs = rsqrtf(s2 * (1.f / 1024.f) - mu * mu + 1e-5f);
    if (tid < 256) {
      int e = h * 256 + tid;
      float y = fmaxf((qrow[e] - mu) * rs * p.qg[e] + p.qbt[e], 0.f);
      qn[tid] = y;
      wr_split(p.xih, p.xil, (size_t)b * 4096 + 1024 + e, y);
    }
    __syncthreads();
    // scores over slots 0..i; scale = 1/(16*0.1) = 0.625
    for (int s = wv; s <= i; s += 8) {
      const float* kp = p.keys + ((size_t)s * 32 + b) * 1024 + h * 256 + lane * 4;
      float4 k4 = *(const float4*)kp;
      float pd = qn[lane * 4] * k4.x + qn[lane * 4 + 1] * k4.y +
                 qn[lane * 4 + 2] * k4.z + qn[lane * 4 + 3] * k4.w;
      pd = wred_add(pd);
      if (lane == 0) sc[s] = pd * 0.625f;
    }
    __syncthreads();
    float mx = (tid <= i) ? sc[tid] : -1e30f;
    mx = bred_max(mx, red, tid);
    float sum = 0.f;
    if (tid <= i) { float e = expf(sc[tid] - mx); sc[tid] = e; sum = e; }
    sum = bred_add(sum, red, tid);
    float inv = 1.f / sum;
    {
      float acc = 0.f;
      int d = tid & 255, half = tid >> 8;
      const float* vp = p.vals + (size_t)b * 1024 + h * 256 + d;
#pragma unroll 4
      for (int s = half; s <= i; s += 2) acc += sc[s] * vp[(size_t)s * 32768];
      pv[tid] = acc;
    }
    __syncthreads();
    if (tid < 256) {
      float val = (pv[tid] + pv[tid + 256]) * inv;
      wr_split(p.xih, p.xil, (size_t)b * 4096 + 2048 + h * 256 + tid, val);
    }
  } else {
    int w = (blk - 128) * 8 + wv;    // 0..1023
    int nt = w & 255, kc = w >> 8;   // kc 0..3, K-chunk 512
    int col0 = (kc < 2) ? kc * 512 : 3072 + (kc - 2) * 512;
    floatx4 c0, c1;
    mm_tile3(p.xih, p.xil, 4096, col0, p.iwh, p.iwl, 4096, nt * 16, col0,
             16, lane, c0, c1);
    store_part(p.ip1 + (size_t)kc * 32 * 4096, 4096, nt, lane, c0, c1);
  }
}

// ---- P3: int-GEMM q+attn half (256 ntiles x 8 ksplit) ---- grid 256
__global__ void __launch_bounds__(512) k_int2(Prm p, int i) {
  const int tid = threadIdx.x, lane = tid & 63, wv = tid >> 6;
  int w = blockIdx.x * 8 + wv;     // 0..2047
  int nt = w & 255, kc = w >> 8;   // kc 0..7, K-chunk 256
  int col0 = 1024 + kc * 256;
  floatx4 c0, c1;
  mm_tile3(p.xih, p.xil, 4096, col0, p.iwh, p.iwl, 4096, nt * 16, col0,
           8, lane, c0, c1);
  store_part(p.ip2 + (size_t)kc * 32 * 4096, 4096, nt, lane, c0, c1);
}

// ---- P4: LN-int (blocks 0..31) || emb gather i+1 (blocks 32..63) ---- grid 64
__global__ void __launch_bounds__(512) k_ln_emb(Prm p, int i) {
  __shared__ float red[8];
  const int blk = blockIdx.x, tid = threadIdx.x;
  if (blk < 32) {
    int b = blk;
    float xs[8], s1 = 0.f, s2 = 0.f;
#pragma unroll
    for (int j = 0; j < 8; ++j) {
      int e = tid + j * 512;
      size_t o = (size_t)b * 4096 + e;
      float x = ((p.ip1[o] + p.ip1[131072 + o]) +
                 (p.ip1[262144 + o] + p.ip1[393216 + o])) +
                ((p.ip2[o] + p.ip2[131072 + o]) +
                 (p.ip2[262144 + o] + p.ip2[393216 + o])) +
                ((p.ip2[524288 + o] + p.ip2[655360 + o]) +
                 (p.ip2[786432 + o] + p.ip2[917504 + o])) + p.ib[e];
      xs[j] = x; s1 += x; s2 += x * x;
    }
    s1 = bred_add(s1, red, tid);
    s2 = bred_add(s2, red, tid);
    float mu = s1 * (1.f / 4096.f);
    float rs = rsqrtf(s2 * (1.f / 4096.f) - mu * mu + 1e-5f);
#pragma unroll
    for (int j = 0; j < 8; ++j) {
      int e = tid + j * 512;
      float y = fmaxf((xs[j] - mu) * rs * p.ig[e] + p.ibt[e], 0.f);
      wr_split(p.interh, p.interl, (size_t)b * 4096 + e, y);
    }
  } else {
    if (i + 1 < 256 && tid < 256) {
      int b = blk - 32;
      int tok = p.obs[(i + 1) * 32 + b];
      float4 e4 = ((const float4*)(p.emb + (size_t)tok * 1024))[tid];
      wr_split4(p.xih, p.xil, (size_t)b * 4096 + 4 * tid, e4);
    }
  }
}

// ---- P5: fin-GEMM (192 ntiles x 8 ksplit) ---- grid 192
__global__ void __launch_bounds__(512) k_fin(Prm p, int i) {
  const int tid = threadIdx.x, lane = tid & 63, wv = tid >> 6;
  int w = blockIdx.x * 8 + wv;     // 0..1535
  int nt = w % 192, kc = w / 192;  // kc 0..7, K-chunk 512
  floatx4 c0, c1;
  mm_tile3(p.interh, p.interl, 4096, kc * 512, p.fwh, p.fwl, 4096, nt * 16,
           kc * 512, 16, lane, c0, c1);
  store_part(p.finpart + (size_t)kc * 32 * 3072, 3072, nt, lane, c0, c1);
}

// ---- P6: merge fin + LN; write keys/vals slot i+1, hidden -> xi & states ---- grid 32
__global__ void __launch_bounds__(512) k_lnfin(Prm p, int i) {
  __shared__ float red[8];
  const int blk = blockIdx.x, tid = threadIdx.x;
  int b = blk;
  float xs[6], s1 = 0.f, s2 = 0.f;
#pragma unroll
  for (int j = 0; j < 6; ++j) {
    int e = tid + j * 512;
    size_t o = (size_t)b * 3072 + e;
    float x = ((p.finpart[o] + p.finpart[98304 + o]) +
               (p.finpart[196608 + o] + p.finpart[294912 + o])) +
              ((p.finpart[393216 + o] + p.finpart[491520 + o]) +
               (p.finpart[589824 + o] + p.finpart[688128 + o])) + p.fb[e];
    xs[j] = x; s1 += x; s2 += x * x;
  }
  s1 = bred_add(s1, red, tid);
  s2 = bred_add(s2, red, tid);
  float mu = s1 * (1.f / 3072.f);
  float rs = rsqrtf(s2 * (1.f / 3072.f) - mu * mu + 1e-5f);
#pragma unroll
  for (int j = 0; j < 6; ++j) {
    int e = tid + j * 512;
    float y = fmaxf((xs[j] - mu) * rs * p.fg[e] + p.fbt[e], 0.f);
    if (j < 2) {
      p.keys[((size_t)(i + 1) * 32 + b) * 1024 + e] = y;
    } else if (j < 4) {
      p.vals[((size_t)(i + 1) * 32 + b) * 1024 + (e - 1024)] = y;
    } else {
      int d = e - 2048;
      wr_split(p.xih, p.xil, (size_t)b * 4096 + 3072 + d, y);
      p.states[((size_t)i * 32 + b) * 1024 + d] = f2bf(y);
    }
  }
}

// ---------------- decoder GEMM: logits = states @ dec_w^T + dec_b ----------------
// M=8192, N=32000, K=1024 bf16. 128x128 tiles, BK=32, dbuf LDS (stride 40), XCD swizzle.
__global__ void __launch_bounds__(256) dec_gemm(const u16* __restrict__ Sm,
                                                const u16* __restrict__ W,
                                                const float* __restrict__ Wb,
                                                float* __restrict__ out) {
  __shared__ u16 As[2][128 * 40];
  __shared__ u16 Bs[2][128 * 40];
  int bid = blockIdx.x;                      // 16000 % 8 == 0
  int swz = (bid & 7) * 2000 + (bid >> 3);
  int mt = swz / 250, nt = swz - mt * 250;
  const int tid = threadIdx.x;
  const int lane = tid & 63, wvi = tid >> 6;
  const int wm = wvi >> 1, wn = wvi & 1;
  const int fr = lane & 15, fg = lane >> 4;

  const int r0 = tid >> 2, k0 = (tid & 3) * 8;
  const u16* pa0 = Sm + (size_t)(mt * 128 + r0) * 1024 + k0;
  const u16* pa1 = pa0 + (size_t)64 * 1024;
  const u16* pb0 = W + (size_t)(nt * 128 + r0) * 1024 + k0;
  const u16* pb1 = pb0 + (size_t)64 * 1024;
  const int da0 = r0 * 40 + k0, da1 = (r0 + 64) * 40 + k0;

  floatx4 acc[4][4];
#pragma unroll
  for (int i = 0; i < 4; ++i)
#pragma unroll
    for (int j = 0; j < 4; ++j) acc[i][j] = floatx4{0.f, 0.f, 0.f, 0.f};

  uint4 ra0 = *(const uint4*)pa0, ra1 = *(const uint4*)pa1;
  uint4 rb0 = *(const uint4*)pb0, rb1 = *(const uint4*)pb1;
  *(uint4*)&As[0][da0] = ra0; *(uint4*)&As[0][da1] = ra1;
  *(uint4*)&Bs[0][da0] = rb0; *(uint4*)&Bs[0][da1] = rb1;
  __syncthreads();

  for (int kt = 0; kt < 32; ++kt) {
    const int cur = kt & 1;
    if (kt < 31) {
      const int off = (kt + 1) * 32;
      ra0 = *(const uint4*)(pa0 + off); ra1 = *(const uint4*)(pa1 + off);
      rb0 = *(const uint4*)(pb0 + off); rb1 = *(const uint4*)(pb1 + off);
    }
    bf16x8 af[4], bfv[4];
#pragma unroll
    for (int i = 0; i < 4; ++i) {
      af[i]  = *(const bf16x8*)&As[cur][(wm * 64 + i * 16 + fr) * 40 + fg * 8];
      bfv[i] = *(const bf16x8*)&Bs[cur][(wn * 64 + i * 16 + fr) * 40 + fg * 8];
    }
#pragma unroll
    for (int i = 0; i < 4; ++i)
#pragma unroll
      for (int j = 0; j < 4; ++j)
        acc[i][j] = __builtin_amdgcn_mfma_f32_16x16x32_bf16(af[i], bfv[j], acc[i][j], 0, 0, 0);
    if (kt < 31) {
      *(uint4*)&As[cur ^ 1][da0] = ra0; *(uint4*)&As[cur ^ 1][da1] = ra1;
      *(uint4*)&Bs[cur ^ 1][da0] = rb0; *(uint4*)&Bs[cur ^ 1][da1] = rb1;
    }
    __syncthreads();
  }

#pragma unroll
  for (int i = 0; i < 4; ++i)
#pragma unroll
    for (int j = 0; j < 4; ++j) {
      int col = nt * 128 + wn * 64 + j * 16 + fr;
      float bias = Wb[col];
#pragma unroll
      for (int r = 0; r < 4; ++r) {
        int row = mt * 128 + wm * 64 + i * 16 + fg * 4 + r;
        out[(size_t)row * 32000 + col] = acc[i][j][r] + bias;
      }
    }
}

extern "C" void kernel_launch(void* const* d_in, const int* in_sizes, int n_in,
                              void* d_out, int out_size, void* d_ws, size_t ws_size,
                              hipStream_t stream) {
  (void)in_sizes; (void)n_in; (void)out_size; (void)ws_size;
  char* ws = (char*)d_ws;
  size_t off = 0;
  auto carve = [&](size_t bytes) {
    void* pp = ws + off;
    off += (bytes + 255) & ~(size_t)255;
    return pp;
  };
  u16* qwh       = (u16*)carve((size_t)1024 * 2048 * 2);
  u16* qwl       = (u16*)carve((size_t)1024 * 2048 * 2);
  u16* iwh       = (u16*)carve((size_t)4096 * 4096 * 2);
  u16* iwl       = (u16*)carve((size_t)4096 * 4096 * 2);
  u16* fwh       = (u16*)carve((size_t)3072 * 4096 * 2);
  u16* fwl       = (u16*)carve((size_t)3072 * 4096 * 2);
  u16* xih       = (u16*)carve((size_t)32 * 4096 * 2);
  u16* xil       = (u16*)carve((size_t)32 * 4096 * 2);
  u16* interh    = (u16*)carve((size_t)32 * 4096 * 2);
  u16* interl    = (u16*)carve((size_t)32 * 4096 * 2);
  float* qpart   = (float*)carve((size_t)8 * 32 * 1024 * 4);
  float* ip1     = (float*)carve((size_t)4 * 32 * 4096 * 4);
  float* ip2     = (float*)carve((size_t)8 * 32 * 4096 * 4);
  float* finpart = (float*)carve((size_t)8 * 32 * 3072 * 4);
  float* keysF   = (float*)carve((size_t)257 * 32 * 1024 * 4);
  float* valsF   = (float*)carve((size_t)257 * 32 * 1024 * 4);
  u16* states    = (u16*)carve((size_t)256 * 32 * 1024 * 2);
  // total ~220 MB. dec_w bf16 (65.5 MB) converted AFTER the RNN into the
  // then-dead q/int weight region at offset 0.
  u16* dw_bf = (u16*)ws;

  // weight hi/lo splits
  cvt_split<<<dim3(512), dim3(256), 0, stream>>>((const float*)d_in[2], qwh, qwl, 1024 * 2048 / 4);
  cvt_split<<<dim3(2048), dim3(256), 0, stream>>>((const float*)d_in[6], iwh, iwl, 4096 * 4096 / 4);
  cvt_split<<<dim3(2048), dim3(256), 0, stream>>>((const float*)d_in[10], fwh, fwl, 3072 * 4096 / 4);

  Prm prm;
  prm.obs = (const int*)d_in[0];
  prm.emb = (const float*)d_in[1];
  prm.qwh = qwh; prm.qwl = qwl;
  prm.qb  = (const float*)d_in[3];
  prm.qg  = (const float*)d_in[4];
  prm.qbt = (const float*)d_in[5];
  prm.iwh = iwh; prm.iwl = iwl;
  prm.ib  = (const float*)d_in[7];
  prm.ig  = (const float*)d_in[8];
  prm.ibt = (const float*)d_in[9];
  prm.fwh = fwh; prm.fwl = fwl;
  prm.fb  = (const float*)d_in[11];
  prm.fg  = (const float*)d_in[12];
  prm.fbt = (const float*)d_in[13];
  prm.hid0 = (const float*)d_in[16];
  prm.key0 = (const float*)d_in[17];
  prm.val0 = (const float*)d_in[18];
  prm.xih = xih; prm.xil = xil; prm.interh = interh; prm.interl = interl;
  prm.states = states; prm.keys = keysF; prm.vals = valsF;
  prm.qpart = qpart; prm.ip1 = ip1; prm.ip2 = ip2; prm.finpart = finpart;

  k_init<<<dim3(64), dim3(512), 0, stream>>>(prm);
  for (int i = 0; i < 256; ++i) {
    k_q<<<dim3(64), dim3(512), 0, stream>>>(prm, i);
    k_attn_int1<<<dim3(256), dim3(512), 0, stream>>>(prm, i);
    k_int2<<<dim3(256), dim3(512), 0, stream>>>(prm, i);
    k_ln_emb<<<dim3(64), dim3(512), 0, stream>>>(prm, i);
    k_fin<<<dim3(192), dim3(512), 0, stream>>>(prm, i);
    k_lnfin<<<dim3(32), dim3(512), 0, stream>>>(prm, i);
  }

  // dec_w fp32 -> bf16 into reused region (q/int weights dead after RNN)
  cvt_bf16<<<dim3(4096), dim3(256), 0, stream>>>((const float*)d_in[14], dw_bf, 32000 * 1024 / 4);

  dec_gemm<<<dim3(16000), dim3(256), 0, stream>>>(
      states, dw_bf, (const float*)d_in[15], (float*)d_out);
}